// Round 18
// baseline (1202.627 us; speedup 1.0000x reference)
//
#include <hip/hip_runtime.h>
#include <math.h>
#include <float.h>

#define NB 8
#define NC 24
#define NA 96
#define NW 96
#define NF 32
#define NHID 128
#define AW (NA*NW)           // 9216
#define NBC (NB*NC)          // 192
#define NEL ((size_t)NBC*AW) // 1769472
#define HSTR 17              // hid LDS row stride in dwords (v10-proven)

// packed fp32: <2 x float> fma -> v_pk_fma_f32 on gfx90a+/gfx950
typedef float v2f __attribute__((ext_vector_type(2)));
typedef float f32x4 __attribute__((ext_vector_type(4)));
typedef short short8_t __attribute__((ext_vector_type(8)));
#ifndef __has_builtin
#define __has_builtin(x) 0
#endif
#if __has_builtin(__builtin_elementwise_fma)
#define PKFMA(a,b,c) __builtin_elementwise_fma((a),(b),(c))
#else
#define PKFMA(a,b,c) ((a)*(b)+(c))
#endif

union frag_u { unsigned int u[4]; short8_t s; };

__device__ __forceinline__ unsigned short bf16rne(float x) {
    unsigned int u = __float_as_uint(x);
    unsigned int r = u + 0x7fffu + ((u >> 16) & 1u);
    return (unsigned short)(r >> 16);
}
__device__ __forceinline__ float bf2f(unsigned short v) {
    return __uint_as_float(((unsigned int)v) << 16);
}
// monotone float<->uint key (handles negatives); key(x1)<key(x2) iff x1<x2
__device__ __forceinline__ unsigned fkey(float x) {
    unsigned u = __float_as_uint(x);
    return (u >> 31) ? ~u : (u | 0x80000000u);
}
__device__ __forceinline__ float funkey(unsigned k) {
    return (k >> 31) ? __uint_as_float(k ^ 0x80000000u) : __uint_as_float(~k);
}
__device__ __forceinline__ float grp16_sum(float v) {
    v += __shfl_xor(v, 1, 64);
    v += __shfl_xor(v, 2, 64);
    v += __shfl_xor(v, 4, 64);
    v += __shfl_xor(v, 8, 64);
    return v;
}
__device__ __forceinline__ float grp16_max(float v) {
    v = fmaxf(v, __shfl_xor(v, 1, 64));
    v = fmaxf(v, __shfl_xor(v, 2, 64));
    v = fmaxf(v, __shfl_xor(v, 4, 64));
    v = fmaxf(v, __shfl_xor(v, 8, 64));
    return v;
}
__device__ __forceinline__ void pack_hilo(float v0, float v1,
                                          unsigned int& hi, unsigned int& lo) {
    asm("v_cvt_pk_bf16_f32 %0, %1, %2" : "=v"(hi) : "v"(v0), "v"(v1));
    float h0 = __uint_as_float(hi << 16);
    float h1 = __uint_as_float(hi & 0xffff0000u);
    float l0 = v0 - h0, l1 = v1 - h1;
    asm("v_cvt_pk_bf16_f32 %0, %1, %2" : "=v"(lo) : "v"(l0), "v"(l1));
}

// ---------------------------------------------------------------- stats
__global__ __launch_bounds__(256) void stats_kernel(
    const float* __restrict__ x, const int* __restrict__ rows_len,
    const int* __restrict__ cols_len, float* __restrict__ stats)
{
    int bc = blockIdx.x;
    int R = rows_len[bc], L = cols_len[bc];
    const float* xp = x + (size_t)bc * AW;
    int n = R * L;
    float sx = 0.f, sxx = 0.f;
    for (int i = threadIdx.x; i < n; i += 256) {
        int a = i / L, w = i - a * L;
        float v = xp[a * NW + w];
        sx += v;
        sxx = fmaf(v, v, sxx);
    }
    __shared__ float r1[256], r2[256];
    r1[threadIdx.x] = sx; r2[threadIdx.x] = sxx;
    __syncthreads();
    for (int s = 128; s > 0; s >>= 1) {
        if (threadIdx.x < s) {
            r1[threadIdx.x] += r1[threadIdx.x + s];
            r2[threadIdx.x] += r2[threadIdx.x + s];
        }
        __syncthreads();
    }
    if (threadIdx.x == 0) {
        float fn = (float)n;
        float mean = r1[0] / fn;
        float var = fmaxf((r2[0] - r1[0] * r1[0] / fn) / (fn - 1.f), 0.f);
        float sd = fmaxf(sqrtf(var), 1e-12f);
        stats[2 * bc] = mean;
        stats[2 * bc + 1] = 1.f / sd;
    }
}

// ---------------------------------------------------------------- prep: transpose first 24 rows of each stack's W1
__global__ __launch_bounds__(256) void prep_kernel(
    const float* __restrict__ tw1, float* __restrict__ w1t)
{
    int i = blockIdx.x * 256 + threadIdx.x;     // [s][j][t]
    if (i >= 4 * NHID * 24) return;
    int s = i / (NHID * 24), r = i % (NHID * 24);
    int j = r / 24, t = r % 24;
    w1t[i] = tw1[(size_t)s * 64 * NHID + t * NHID + j];
}

// ---------------------------------------------------------------- prep2: split W2^T into bf16 hi/lo (per stack)
__global__ __launch_bounds__(256) void prep2_kernel(
    const float* __restrict__ tw2, unsigned short* __restrict__ w2bf)
{
    int i = blockIdx.x * 256 + threadIdx.x;
    if (i >= 4 * NF * NHID) return;
    int s = i / (NF * NHID), r = i % (NF * NHID);
    int f = r / NHID, j = r % NHID;
    float v = tw2[((size_t)s * NHID + j) * NF + f];
    unsigned short hi = bf16rne(v);
    unsigned short lo = bf16rne(v - bf2f(hi));
    size_t base = (size_t)s * (2 * NF * NHID) + (size_t)f * NHID + j;
    w2bf[base] = hi;
    w2bf[base + NF * NHID] = lo;
}

// ---------------------------------------------------------------- prep2t: split t0_w2 into bf16 hi/lo
__global__ __launch_bounds__(256) void prep2t_kernel(
    const float* __restrict__ t0w2, unsigned short* __restrict__ w2bf)
{
    int i = blockIdx.x * 256 + threadIdx.x;
    if (i >= NF * NHID) return;
    int f = i / NHID, j = i % NHID;
    float v = t0w2[(size_t)j * NF + f];
    unsigned short hi = bf16rne(v);
    unsigned short lo = bf16rne(v - bf2f(hi));
    w2bf[(size_t)f * NHID + j] = hi;
    w2bf[(size_t)NF * NHID + f * NHID + j] = lo;
}

// ---------------------------------------------------------------- t0 v3: MFMA layer-2 (mlp template) + fused stack-0 pools
// Phase A: hidden = relu(xn*w1[j]+b1[j]) (scalar x, no seed loads) -> bf16
// hi/lo -> LDS. Phase B + pool epilogue copied from the proven mlp kernel.
// No residual read (h fresh); h written bf16.
__global__ __launch_bounds__(256, 4) void t0_kernel(
    const float* __restrict__ x, const int* __restrict__ rows_len,
    const int* __restrict__ cols_len, const float* __restrict__ stats,
    const float* __restrict__ w1, const float* __restrict__ b1,
    const unsigned short* __restrict__ w2bf, const float* __restrict__ b2,
    unsigned short* __restrict__ h, float* __restrict__ rowsum,
    float* __restrict__ colsum, float* __restrict__ matsum,
    unsigned* __restrict__ cmax_key)
{
    __shared__ unsigned int hid_hi[256 * HSTR];
    __shared__ unsigned int hid_lo[256 * HSTR];

    int tid = threadIdx.x;
    int bc = blockIdx.x / 36;
    int blk36 = blockIdx.x % 36;
    int base = blk36 * 256;
    int lane = tid & 63, wv = tid >> 6;
    int g = lane >> 4, c16 = lane & 15;

    int e = base + tid;
    int a = e / NW, wc = e - a * NW;
    int R = rows_len[bc], L = cols_len[bc];
    float mean = stats[2 * bc], rstd = stats[2 * bc + 1];
    bool valid = (a < R) && (wc < L);
    float xn = valid ? (x[(size_t)bc * AW + e] - mean) * rstd : 0.f;
    unsigned short* hp = h + (size_t)bc * NF * AW;

    const unsigned short* w2hi = w2bf;
    const unsigned short* w2lo = w2bf + NF * NHID;

    f32x4 acc[4][2];
    #pragma unroll
    for (int t = 0; t < 2; t++) {
        f32x4 bb = *(const f32x4*)(b2 + 16 * t + 4 * g);
        #pragma unroll
        for (int ti = 0; ti < 4; ti++) acc[ti][t] = bb;
    }

    for (int w = 0; w < 4; w++) {
        int jw = 32 * w;
        frag_u Ah[2], Al[2];
        #pragma unroll
        for (int t = 0; t < 2; t++) {
            size_t off = (size_t)(c16 + 16 * t) * NHID + jw + 8 * g;
            const unsigned int* ph = (const unsigned int*)(w2hi + off);
            const unsigned int* pl = (const unsigned int*)(w2lo + off);
            #pragma unroll
            for (int d = 0; d < 4; d++) { Ah[t].u[d] = ph[d]; Al[t].u[d] = pl[d]; }
        }

        #pragma unroll 4
        for (int jp = 0; jp < 16; jp++) {
            int j0 = jw + 2 * jp;
            float v0 = fmaxf(fmaf(xn, w1[j0], b1[j0]), 0.f);
            float v1 = fmaxf(fmaf(xn, w1[j0 + 1], b1[j0 + 1]), 0.f);
            unsigned int hi, lo;
            pack_hilo(v0, v1, hi, lo);
            hid_hi[tid * HSTR + jp] = hi;
            hid_lo[tid * HSTR + jp] = lo;
        }
        __syncthreads();

        #pragma unroll
        for (int ti = 0; ti < 4; ti++) {
            int el = (wv * 4 + ti) * 16 + c16;
            const unsigned int* bh = &hid_hi[el * HSTR + 4 * g];
            const unsigned int* bl = &hid_lo[el * HSTR + 4 * g];
            frag_u Bh, Bl;
            #pragma unroll
            for (int d = 0; d < 4; d++) { Bh.u[d] = bh[d]; Bl.u[d] = bl[d]; }
            #pragma unroll
            for (int t = 0; t < 2; t++) {
                acc[ti][t] = __builtin_amdgcn_mfma_f32_16x16x32_bf16(Ah[t].s, Bh.s, acc[ti][t], 0, 0, 0);
                acc[ti][t] = __builtin_amdgcn_mfma_f32_16x16x32_bf16(Al[t].s, Bh.s, acc[ti][t], 0, 0, 0);
                acc[ti][t] = __builtin_amdgcn_mfma_f32_16x16x32_bf16(Ah[t].s, Bl.s, acc[ti][t], 0, 0, 0);
            }
        }
        __syncthreads();
    }

    // ---- pool LDS accumulators (alias dead hid_hi)
    float* col_lds = (float*)hid_hi;
    float* row_lds = col_lds + 96 * 9;
    float* mat_lds = row_lds + 32;
    unsigned* max_lds = (unsigned*)(mat_lds + 8);
    for (int i = tid; i < 96 * 9 + 32 + 8 + 32; i += 256) col_lds[i] = 0.f;
    __syncthreads();

    int a0 = base / NW;
    float matp[2] = {0.f, 0.f};
    float mxp[2][4];
    #pragma unroll
    for (int t = 0; t < 2; t++)
        #pragma unroll
        for (int r = 0; r < 4; r++) mxp[t][r] = -FLT_MAX;

    #pragma unroll
    for (int ti = 0; ti < 4; ti++) {
        int el = (wv * 4 + ti) * 16 + c16;
        int ee = base + el;
        int aa = ee / NW, ww = ee - aa * NW;
        float mk = (aa < R && ww < L) ? 1.f : 0.f;
        float rowv[2];
        #pragma unroll
        for (int t = 0; t < 2; t++) {
            #pragma unroll
            for (int r = 0; r < 4; r++) {
                int f = 4 * g + r + 16 * t;
                float hv = acc[ti][t][r] * mk;
                hp[(size_t)f * AW + ee] = bf16rne(hv);
                mxp[t][r] = fmaxf(mxp[t][r], hv);
                if (r == 1)      rowv[t] = __sinf(hv);
                else if (r == 2) atomicAdd(&col_lds[ww * 9 + g + 4 * t], __sinf(hv));
                else if (r == 3) matp[t] += __sinf(hv);
            }
        }
        #pragma unroll
        for (int t = 0; t < 2; t++) {
            float v = grp16_sum(rowv[t]);
            if (c16 == 0) atomicAdd(&row_lds[(aa - a0) * 8 + g + 4 * t], v);
        }
    }

    #pragma unroll
    for (int t = 0; t < 2; t++) {
        float v = grp16_sum(matp[t]);
        if (c16 == 0) atomicAdd(&mat_lds[g + 4 * t], v);
        #pragma unroll
        for (int r = 0; r < 4; r++) {
            float m = grp16_max(mxp[t][r]);
            if (c16 == 0) atomicMax(&max_lds[4 * g + r + 16 * t], fkey(m));
        }
    }
    __syncthreads();
    if (tid < 32) {
        int ar = a0 + (tid >> 3);
        if (ar < NA) atomicAdd(&rowsum[(bc * NA + ar) * 8 + (tid & 7)], row_lds[tid]);
    }
    if (tid < 8) atomicAdd(&matsum[bc * 8 + tid], mat_lds[tid]);
    if (tid >= 32 && tid < 64) atomicMax(&cmax_key[bc * NF + tid - 32], max_lds[tid - 32]);
    for (int i = tid; i < NW * 8; i += 256)
        atomicAdd(&colsum[bc * NW * 8 + i], col_lds[(i >> 3) * 9 + (i & 7)]);
}

// ---------------------------------------------------------------- precompute per-(bc): rowc[j][a], colc[j][w]
__global__ __launch_bounds__(256) void precomp_kernel(
    const float* __restrict__ rowsum, const float* __restrict__ colsum,
    const float* __restrict__ matsum, const unsigned* __restrict__ cmax_key,
    const float* __restrict__ w1, const float* __restrict__ b1,
    float* __restrict__ rowc, float* __restrict__ colc)
{
    __shared__ float sbm[NF];
    __shared__ float sconst[NHID];
    __shared__ float scs[NW * 8];
    int tid = threadIdx.x;
    int bc = blockIdx.x, b = bc / NC;

    for (int i = tid; i < NW * 8; i += 256) scs[i] = colsum[bc * NW * 8 + i];
    if (tid < NF) {
        unsigned km = cmax_key[(b * NC) * NF + tid];
        for (int c = 1; c < NC; c++) {
            unsigned kc = cmax_key[(b * NC + c) * NF + tid];
            km = (kc > km) ? kc : km;
        }
        sbm[tid] = funkey(km);
    }
    __syncthreads();
    if (tid < NHID) {
        float v = b1[tid];
        const float* mp = matsum + bc * 8;
        #pragma unroll
        for (int k = 0; k < 8; k++) v = fmaf(mp[k], w1[(24 + k) * NHID + tid], v);
        #pragma unroll
        for (int f = 0; f < NF; f++) v = fmaf(sbm[f], w1[(32 + f) * NHID + tid], v);
        sconst[tid] = v;
    }
    __syncthreads();
    for (int i = tid; i < NHID * NA; i += 256) {
        int j = i / NA, aa = i - j * NA;
        const float* rp = rowsum + (bc * NA + aa) * 8;
        float v = sconst[j];
        #pragma unroll
        for (int k = 0; k < 8; k++) v = fmaf(rp[k], w1[(8 + k) * NHID + j], v);
        rowc[(size_t)bc * (NHID * NA) + i] = v;
    }
    for (int i = tid; i < NHID * NW; i += 256) {
        int j = i / NW, ww = i - j * NW;
        float v = 0.f;
        #pragma unroll
        for (int k = 0; k < 8; k++) v = fmaf(scs[ww * 8 + k], w1[(16 + k) * NHID + j], v);
        colc[(size_t)bc * (NHID * NW) + i] = v;
    }
}

// ---------------------------------------------------------------- shared mlp core (phases A+B), returns acc
__device__ __forceinline__ void mlp_core(
    int tid, int bc, int base, int a, int wc, int g, int c16, int wv,
    const unsigned short* hp, const float* rcr, const float* rcc,
    const float* __restrict__ w1t, const unsigned short* __restrict__ w2bf,
    const float* __restrict__ b2, unsigned int* hid_hi, unsigned int* hid_lo,
    f32x4 (&acc)[4][2])
{
    int e = base + tid;
    float p[8];
    #pragma unroll
    for (int k = 0; k < 8; k++) p[k] = __sinf(bf2f(hp[(size_t)(4 * k) * AW + e]));
    v2f p2[4];
    #pragma unroll
    for (int t = 0; t < 4; t++) p2[t] = (v2f){p[2 * t], p[2 * t + 1]};

    const unsigned short* w2hi = w2bf;
    const unsigned short* w2lo = w2bf + NF * NHID;

    #pragma unroll
    for (int t = 0; t < 2; t++) {
        f32x4 bb = *(const f32x4*)(b2 + 16 * t + 4 * g);
        #pragma unroll
        for (int ti = 0; ti < 4; ti++) acc[ti][t] = bb;
    }

    for (int w = 0; w < 4; w++) {
        int jw = 32 * w;
        frag_u Ah[2], Al[2];
        #pragma unroll
        for (int t = 0; t < 2; t++) {
            size_t off = (size_t)(c16 + 16 * t) * NHID + jw + 8 * g;
            const unsigned int* ph = (const unsigned int*)(w2hi + off);
            const unsigned int* pl = (const unsigned int*)(w2lo + off);
            #pragma unroll
            for (int d = 0; d < 4; d++) { Ah[t].u[d] = ph[d]; Al[t].u[d] = pl[d]; }
        }

        #pragma unroll 4
        for (int jp = 0; jp < 16; jp++) {
            int jl = 2 * jp;
            const v2f* w1r0 = (const v2f*)(w1t + (size_t)(jw + jl) * 24);
            const v2f* w1r1 = w1r0 + 12;
            v2f u0 = {rcr[(size_t)(jw + jl) * NA + a], rcc[(size_t)(jw + jl) * NW + wc]};
            v2f u1 = {rcr[(size_t)(jw + jl + 1) * NA + a], rcc[(size_t)(jw + jl + 1) * NW + wc]};
            #pragma unroll
            for (int t = 0; t < 4; t++) {
                u0 = PKFMA(p2[t], w1r0[t], u0);
                u1 = PKFMA(p2[t], w1r1[t], u1);
            }
            float v0 = fmaxf(u0.x + u0.y, 0.f);
            float v1 = fmaxf(u1.x + u1.y, 0.f);
            unsigned int hi, lo;
            pack_hilo(v0, v1, hi, lo);
            hid_hi[tid * HSTR + jp] = hi;
            hid_lo[tid * HSTR + jp] = lo;
        }
        __syncthreads();

        #pragma unroll
        for (int ti = 0; ti < 4; ti++) {
            int el = (wv * 4 + ti) * 16 + c16;
            const unsigned int* bh = &hid_hi[el * HSTR + 4 * g];
            const unsigned int* bl = &hid_lo[el * HSTR + 4 * g];
            frag_u Bh, Bl;
            #pragma unroll
            for (int d = 0; d < 4; d++) { Bh.u[d] = bh[d]; Bl.u[d] = bl[d]; }
            #pragma unroll
            for (int t = 0; t < 2; t++) {
                acc[ti][t] = __builtin_amdgcn_mfma_f32_16x16x32_bf16(Ah[t].s, Bh.s, acc[ti][t], 0, 0, 0);
                acc[ti][t] = __builtin_amdgcn_mfma_f32_16x16x32_bf16(Al[t].s, Bh.s, acc[ti][t], 0, 0, 0);
                acc[ti][t] = __builtin_amdgcn_mfma_f32_16x16x32_bf16(Ah[t].s, Bl.s, acc[ti][t], 0, 0, 0);
            }
        }
        __syncthreads();
    }
}

// ---------------------------------------------------------------- mlp_mid: stacks 0..2 — write h + fused pools
__global__ __launch_bounds__(256, 4) void mlp_mid_kernel(
    unsigned short* __restrict__ h, const float* __restrict__ rowc,
    const float* __restrict__ colc, const int* __restrict__ rows_len,
    const int* __restrict__ cols_len, const float* __restrict__ w1t,
    const unsigned short* __restrict__ w2bf, const float* __restrict__ b2,
    float* __restrict__ rowsum, float* __restrict__ colsum,
    float* __restrict__ matsum, unsigned* __restrict__ cmax_key)
{
    __shared__ unsigned int hid_hi[256 * HSTR];
    __shared__ unsigned int hid_lo[256 * HSTR];

    int tid = threadIdx.x;
    int bc = blockIdx.x / 36;
    int blk36 = blockIdx.x % 36;
    int base = blk36 * 256;
    int lane = tid & 63, wv = tid >> 6;
    int g = lane >> 4, c16 = lane & 15;
    int e = base + tid;
    int a = e / NW, wc = e - a * NW;
    unsigned short* hp = h + (size_t)bc * NF * AW;
    const float* rcr = rowc + (size_t)bc * (NHID * NA);
    const float* rcc = colc + (size_t)bc * (NHID * NW);

    f32x4 acc[4][2];
    mlp_core(tid, bc, base, a, wc, g, c16, wv, hp, rcr, rcc, w1t, w2bf, b2,
             hid_hi, hid_lo, acc);

    float* col_lds = (float*)hid_hi;
    float* row_lds = col_lds + 96 * 9;
    float* mat_lds = row_lds + 32;
    unsigned* max_lds = (unsigned*)(mat_lds + 8);
    for (int i = tid; i < 96 * 9 + 32 + 8 + 32; i += 256) col_lds[i] = 0.f;
    __syncthreads();

    int R = rows_len[bc], L = cols_len[bc];
    int a0 = base / NW;
    float matp[2] = {0.f, 0.f};
    float mxp[2][4];
    #pragma unroll
    for (int t = 0; t < 2; t++)
        #pragma unroll
        for (int r = 0; r < 4; r++) mxp[t][r] = -FLT_MAX;

    #pragma unroll
    for (int ti = 0; ti < 4; ti++) {
        int el = (wv * 4 + ti) * 16 + c16;
        int ee = base + el;
        int aa = ee / NW, ww = ee - aa * NW;
        float mk = (aa < R && ww < L) ? 1.f : 0.f;
        float rowv[2];
        #pragma unroll
        for (int t = 0; t < 2; t++) {
            #pragma unroll
            for (int r = 0; r < 4; r++) {
                int f = 4 * g + r + 16 * t;
                unsigned short* ad = hp + (size_t)f * AW + ee;
                float hv = (bf2f(*ad) + acc[ti][t][r]) * mk;
                *ad = bf16rne(hv);
                mxp[t][r] = fmaxf(mxp[t][r], hv);
                if (r == 1)      rowv[t] = __sinf(hv);
                else if (r == 2) atomicAdd(&col_lds[ww * 9 + g + 4 * t], __sinf(hv));
                else if (r == 3) matp[t] += __sinf(hv);
            }
        }
        #pragma unroll
        for (int t = 0; t < 2; t++) {
            float v = grp16_sum(rowv[t]);
            if (c16 == 0) atomicAdd(&row_lds[(aa - a0) * 8 + g + 4 * t], v);
        }
    }

    #pragma unroll
    for (int t = 0; t < 2; t++) {
        float v = grp16_sum(matp[t]);
        if (c16 == 0) atomicAdd(&mat_lds[g + 4 * t], v);
        #pragma unroll
        for (int r = 0; r < 4; r++) {
            float m = grp16_max(mxp[t][r]);
            if (c16 == 0) atomicMax(&max_lds[4 * g + r + 16 * t], fkey(m));
        }
    }
    __syncthreads();
    if (tid < 32) {
        int ar = a0 + (tid >> 3);
        if (ar < NA) atomicAdd(&rowsum[(bc * NA + ar) * 8 + (tid & 7)], row_lds[tid]);
    }
    if (tid < 8) atomicAdd(&matsum[bc * 8 + tid], mat_lds[tid]);
    if (tid >= 32 && tid < 64) atomicMax(&cmax_key[bc * NF + tid - 32], max_lds[tid - 32]);
    for (int i = tid; i < NW * 8; i += 256)
        atomicAdd(&colsum[bc * NW * 8 + i], col_lds[(i >> 3) * 9 + (i & 7)]);
}

// ---------------------------------------------------------------- mlp_last: stack 3 — sqsum only, no h write
__global__ __launch_bounds__(256, 4) void mlp_last_kernel(
    unsigned short* __restrict__ h, const float* __restrict__ rowc,
    const float* __restrict__ colc, const int* __restrict__ rows_len,
    const int* __restrict__ cols_len, const float* __restrict__ w1t,
    const unsigned short* __restrict__ w2bf, const float* __restrict__ b2,
    float* __restrict__ sqsum)
{
    __shared__ unsigned int hid_hi[256 * HSTR];
    __shared__ unsigned int hid_lo[256 * HSTR];

    int tid = threadIdx.x;
    int bc = blockIdx.x / 36;
    int blk36 = blockIdx.x % 36;
    int base = blk36 * 256;
    int lane = tid & 63, wv = tid >> 6;
    int g = lane >> 4, c16 = lane & 15;
    int e = base + tid;
    int a = e / NW, wc = e - a * NW;
    unsigned short* hp = h + (size_t)bc * NF * AW;
    const float* rcr = rowc + (size_t)bc * (NHID * NA);
    const float* rcc = colc + (size_t)bc * (NHID * NW);

    f32x4 acc[4][2];
    mlp_core(tid, bc, base, a, wc, g, c16, wv, hp, rcr, rcc, w1t, w2bf, b2,
             hid_hi, hid_lo, acc);

    int R = rows_len[bc], L = cols_len[bc];
    float psum[2][4] = {{0.f, 0.f, 0.f, 0.f}, {0.f, 0.f, 0.f, 0.f}};
    #pragma unroll
    for (int ti = 0; ti < 4; ti++) {
        int el = (wv * 4 + ti) * 16 + c16;
        int ee = base + el;
        int aa = ee / NW, ww = ee - aa * NW;
        float mk = (aa < R && ww < L) ? 1.f : 0.f;
        #pragma unroll
        for (int t = 0; t < 2; t++) {
            #pragma unroll
            for (int r = 0; r < 4; r++) {
                int f = 4 * g + r + 16 * t;
                float hv = (bf2f(hp[(size_t)f * AW + ee]) + acc[ti][t][r]) * mk;
                psum[t][r] = fmaf(hv, hv, psum[t][r]);
            }
        }
    }
    float* sq_lds = (float*)hid_hi;
    if (tid < NF) sq_lds[tid] = 0.f;
    __syncthreads();
    #pragma unroll
    for (int t = 0; t < 2; t++) {
        #pragma unroll
        for (int r = 0; r < 4; r++) {
            float v = grp16_sum(psum[t][r]);
            if (c16 == 0) atomicAdd(&sq_lds[4 * g + r + 16 * t], v);
        }
    }
    __syncthreads();
    if (tid < NF) atomicAdd(&sqsum[bc * NF + tid], sq_lds[tid]);
}

// ---------------------------------------------------------------- final: rms from sqsum + mean-over-C + MLP + tanh
__global__ __launch_bounds__(64) void out_kernel(
    const float* __restrict__ sqsum, const int* __restrict__ rows_len,
    const int* __restrict__ cols_len, const float* __restrict__ w1,
    const float* __restrict__ b1, const float* __restrict__ w2,
    const float* __restrict__ b2, float* __restrict__ out)
{
    int b = threadIdx.x;
    if (b >= NB) return;
    float hm[NF];
    #pragma unroll
    for (int f = 0; f < NF; f++) hm[f] = 0.f;
    for (int c = 0; c < NC; c++) {
        int bc = b * NC + c;
        float n = (float)(rows_len[bc] * cols_len[bc]);
        float rdn = 1.f / fmaxf(n, 1e-12f);
        #pragma unroll
        for (int f = 0; f < NF; f++) {
            float q = fmaxf(sqsum[bc * NF + f], 1e-20f);
            hm[f] += sqrtf(q * rdn);
        }
    }
    #pragma unroll
    for (int f = 0; f < NF; f++) hm[f] *= (1.f / (float)NC);

    float o0 = b2[0], o1 = b2[1];
    for (int j = 0; j < NHID; j++) {
        float v = b1[j];
        #pragma unroll
        for (int f = 0; f < NF; f++) v = fmaf(hm[f], w1[f * NHID + j], v);
        v = fmaxf(v, 0.f);
        o0 = fmaf(v, w2[j * 2 + 0], o0);
        o1 = fmaf(v, w2[j * 2 + 1], o1);
    }
    out[b * 2 + 0] = 8.f * tanhf(o0);
    out[b * 2 + 1] = 8.f * tanhf(o1);
}

// ---------------------------------------------------------------- launcher
extern "C" void kernel_launch(void* const* d_in, const int* in_sizes, int n_in,
                              void* d_out, int out_size, void* d_ws, size_t ws_size,
                              hipStream_t stream)
{
    const float* x    = (const float*)d_in[0];
    const int* rl     = (const int*)d_in[1];
    const int* cl     = (const int*)d_in[2];
    const float* t0w1 = (const float*)d_in[3];
    const float* t0b1 = (const float*)d_in[4];
    const float* t0w2 = (const float*)d_in[5];
    const float* t0b2 = (const float*)d_in[6];
    const float* tw1  = (const float*)d_in[7];
    const float* tb1  = (const float*)d_in[8];
    const float* tw2  = (const float*)d_in[9];
    const float* tb2  = (const float*)d_in[10];
    const float* ow1  = (const float*)d_in[11];
    const float* ob1  = (const float*)d_in[12];
    const float* ow2  = (const float*)d_in[13];
    const float* ob2  = (const float*)d_in[14];
    float* out = (float*)d_out;

    float* ws    = (float*)d_ws;
    unsigned short* h = (unsigned short*)ws;         // NEL*NF ushorts (region sized as floats; half used)
    float* stats = ws + NEL * NF;                    // 2*NBC
    // --- contiguous accumulator region (single small memset per stack) ---
    float*    rowb = stats + 2 * NBC;                // NBC*NA*8 = 147456
    float*    matb = rowb + (size_t)NBC * NA * 8;    // NBC*8    = 1536
    unsigned* cmxb = (unsigned*)(matb + NBC * 8);    // NBC*NF   = 6144
    float*    colb = (float*)(cmxb + NBC * NF);      // NBC*NW*8 = 147456
    size_t    accum_floats = (size_t)NBC * NA * 8 + NBC * 8 + NBC * NF
                           + (size_t)NBC * NW * 8;   // 302592 floats = 1.2 MB
    // --- rest ---
    float* sqb   = colb + (size_t)NBC * NW * 8;      // NBC*NF
    float* w1tb  = sqb + NBC * NF;                   // 4*NHID*24
    float* rowcb = w1tb + 4 * NHID * 24;             // NBC*NHID*NA
    float* colcb = rowcb + (size_t)NBC * NHID * NA;  // NBC*NHID*NW
    unsigned short* w2bfb = (unsigned short*)(colcb + (size_t)NBC * NHID * NW); // 4*2*NF*NHID
    unsigned short* w2t0b = w2bfb + (size_t)4 * 2 * NF * NHID;                  // 2*NF*NHID

    hipMemsetAsync(sqb, 0, NBC * NF * sizeof(float), stream);
    hipMemsetAsync(rowb, 0, accum_floats * sizeof(float), stream);  // for t0's fused pools
    stats_kernel<<<NBC, 256, 0, stream>>>(x, rl, cl, stats);
    prep_kernel<<<(4 * NHID * 24 + 255) / 256, 256, 0, stream>>>(tw1, w1tb);
    prep2_kernel<<<(4 * NF * NHID + 255) / 256, 256, 0, stream>>>(tw2, w2bfb);
    prep2t_kernel<<<(NF * NHID + 255) / 256, 256, 0, stream>>>(t0w2, w2t0b);
    t0_kernel<<<NBC * 36, 256, 0, stream>>>(x, rl, cl, stats,
                                            t0w1, t0b1, w2t0b, t0b2, h,
                                            rowb, colb, matb, cmxb);
    for (int s = 0; s < 4; s++) {
        precomp_kernel<<<NBC, 256, 0, stream>>>(rowb, colb, matb, cmxb,
            tw1 + (size_t)s * 64 * NHID, tb1 + s * NHID, rowcb, colcb);
        if (s < 3) {
            hipMemsetAsync(rowb, 0, accum_floats * sizeof(float), stream);
            mlp_mid_kernel<<<NBC * 36, 256, 0, stream>>>(h, rowcb, colcb, rl, cl,
                w1tb + (size_t)s * NHID * 24,
                w2bfb + (size_t)s * (2 * NF * NHID),
                tb2 + s * NF, rowb, colb, matb, cmxb);
        } else {
            mlp_last_kernel<<<NBC * 36, 256, 0, stream>>>(h, rowcb, colcb, rl, cl,
                w1tb + (size_t)s * NHID * 24,
                w2bfb + (size_t)s * (2 * NF * NHID),
                tb2 + s * NF, sqb);
        }
    }
    out_kernel<<<1, 64, 0, stream>>>(sqb, rl, cl, ow1, ob1, ow2, ob2, out);
}

// Round 19
// 1180.032 us; speedup vs baseline: 1.0191x; 1.0191x over previous
//
#include <hip/hip_runtime.h>
#include <math.h>
#include <float.h>

#define NB 8
#define NC 24
#define NA 96
#define NW 96
#define NF 32
#define NHID 128
#define AW (NA*NW)           // 9216
#define NBC (NB*NC)          // 192
#define NEL ((size_t)NBC*AW) // 1769472
#define HSTR 17              // hid LDS row stride in dwords (v10-proven)

// packed fp32: <2 x float> fma -> v_pk_fma_f32 on gfx90a+/gfx950
typedef float v2f __attribute__((ext_vector_type(2)));
typedef float f32x4 __attribute__((ext_vector_type(4)));
typedef short short8_t __attribute__((ext_vector_type(8)));
#ifndef __has_builtin
#define __has_builtin(x) 0
#endif
#if __has_builtin(__builtin_elementwise_fma)
#define PKFMA(a,b,c) __builtin_elementwise_fma((a),(b),(c))
#else
#define PKFMA(a,b,c) ((a)*(b)+(c))
#endif

union frag_u { unsigned int u[4]; short8_t s; };

__device__ __forceinline__ unsigned short bf16rne(float x) {
    unsigned int u = __float_as_uint(x);
    unsigned int r = u + 0x7fffu + ((u >> 16) & 1u);
    return (unsigned short)(r >> 16);
}
__device__ __forceinline__ float bf2f(unsigned short v) {
    return __uint_as_float(((unsigned int)v) << 16);
}
// monotone float<->uint key (handles negatives); key(x1)<key(x2) iff x1<x2
__device__ __forceinline__ unsigned fkey(float x) {
    unsigned u = __float_as_uint(x);
    return (u >> 31) ? ~u : (u | 0x80000000u);
}
__device__ __forceinline__ float funkey(unsigned k) {
    return (k >> 31) ? __uint_as_float(k ^ 0x80000000u) : __uint_as_float(~k);
}
__device__ __forceinline__ float grp16_sum(float v) {
    v += __shfl_xor(v, 1, 64);
    v += __shfl_xor(v, 2, 64);
    v += __shfl_xor(v, 4, 64);
    v += __shfl_xor(v, 8, 64);
    return v;
}
__device__ __forceinline__ float grp16_max(float v) {
    v = fmaxf(v, __shfl_xor(v, 1, 64));
    v = fmaxf(v, __shfl_xor(v, 2, 64));
    v = fmaxf(v, __shfl_xor(v, 4, 64));
    v = fmaxf(v, __shfl_xor(v, 8, 64));
    return v;
}
__device__ __forceinline__ void pack_hilo(float v0, float v1,
                                          unsigned int& hi, unsigned int& lo) {
    asm("v_cvt_pk_bf16_f32 %0, %1, %2" : "=v"(hi) : "v"(v0), "v"(v1));
    float h0 = __uint_as_float(hi << 16);
    float h1 = __uint_as_float(hi & 0xffff0000u);
    float l0 = v0 - h0, l1 = v1 - h1;
    asm("v_cvt_pk_bf16_f32 %0, %1, %2" : "=v"(lo) : "v"(l0), "v"(l1));
}

// ---------------------------------------------------------------- stats
__global__ __launch_bounds__(256) void stats_kernel(
    const float* __restrict__ x, const int* __restrict__ rows_len,
    const int* __restrict__ cols_len, float* __restrict__ stats)
{
    int bc = blockIdx.x;
    int R = rows_len[bc], L = cols_len[bc];
    const float* xp = x + (size_t)bc * AW;
    int n = R * L;
    float sx = 0.f, sxx = 0.f;
    for (int i = threadIdx.x; i < n; i += 256) {
        int a = i / L, w = i - a * L;
        float v = xp[a * NW + w];
        sx += v;
        sxx = fmaf(v, v, sxx);
    }
    __shared__ float r1[256], r2[256];
    r1[threadIdx.x] = sx; r2[threadIdx.x] = sxx;
    __syncthreads();
    for (int s = 128; s > 0; s >>= 1) {
        if (threadIdx.x < s) {
            r1[threadIdx.x] += r1[threadIdx.x + s];
            r2[threadIdx.x] += r2[threadIdx.x + s];
        }
        __syncthreads();
    }
    if (threadIdx.x == 0) {
        float fn = (float)n;
        float mean = r1[0] / fn;
        float var = fmaxf((r2[0] - r1[0] * r1[0] / fn) / (fn - 1.f), 0.f);
        float sd = fmaxf(sqrtf(var), 1e-12f);
        stats[2 * bc] = mean;
        stats[2 * bc + 1] = 1.f / sd;
    }
}

// ---------------------------------------------------------------- prep: transpose first 24 rows of each stack's W1
__global__ __launch_bounds__(256) void prep_kernel(
    const float* __restrict__ tw1, float* __restrict__ w1t)
{
    int i = blockIdx.x * 256 + threadIdx.x;     // [s][j][t]
    if (i >= 4 * NHID * 24) return;
    int s = i / (NHID * 24), r = i % (NHID * 24);
    int j = r / 24, t = r % 24;
    w1t[i] = tw1[(size_t)s * 64 * NHID + t * NHID + j];
}

// ---------------------------------------------------------------- prep2: split W2^T into bf16 hi/lo (per stack)
__global__ __launch_bounds__(256) void prep2_kernel(
    const float* __restrict__ tw2, unsigned short* __restrict__ w2bf)
{
    int i = blockIdx.x * 256 + threadIdx.x;
    if (i >= 4 * NF * NHID) return;
    int s = i / (NF * NHID), r = i % (NF * NHID);
    int f = r / NHID, j = r % NHID;
    float v = tw2[((size_t)s * NHID + j) * NF + f];
    unsigned short hi = bf16rne(v);
    unsigned short lo = bf16rne(v - bf2f(hi));
    size_t base = (size_t)s * (2 * NF * NHID) + (size_t)f * NHID + j;
    w2bf[base] = hi;
    w2bf[base + NF * NHID] = lo;
}

// ---------------------------------------------------------------- prep2t: split t0_w2 into bf16 hi/lo
__global__ __launch_bounds__(256) void prep2t_kernel(
    const float* __restrict__ t0w2, unsigned short* __restrict__ w2bf)
{
    int i = blockIdx.x * 256 + threadIdx.x;
    if (i >= NF * NHID) return;
    int f = i / NHID, j = i % NHID;
    float v = t0w2[(size_t)j * NF + f];
    unsigned short hi = bf16rne(v);
    unsigned short lo = bf16rne(v - bf2f(hi));
    w2bf[(size_t)f * NHID + j] = hi;
    w2bf[(size_t)NF * NHID + f * NHID + j] = lo;
}

// ---------------------------------------------------------------- t0 v3: MFMA layer-2 (mlp template) + fused stack-0 pools
__global__ __launch_bounds__(256, 4) void t0_kernel(
    const float* __restrict__ x, const int* __restrict__ rows_len,
    const int* __restrict__ cols_len, const float* __restrict__ stats,
    const float* __restrict__ w1, const float* __restrict__ b1,
    const unsigned short* __restrict__ w2bf, const float* __restrict__ b2,
    unsigned short* __restrict__ h, float* __restrict__ rowsum,
    float* __restrict__ colsum, float* __restrict__ matsum,
    unsigned* __restrict__ cmax_key)
{
    __shared__ unsigned int hid_hi[256 * HSTR];
    __shared__ unsigned int hid_lo[256 * HSTR];

    int tid = threadIdx.x;
    int bc = blockIdx.x / 36;
    int blk36 = blockIdx.x % 36;
    int base = blk36 * 256;
    int lane = tid & 63, wv = tid >> 6;
    int g = lane >> 4, c16 = lane & 15;

    int e = base + tid;
    int a = e / NW, wc = e - a * NW;
    int R = rows_len[bc], L = cols_len[bc];
    float mean = stats[2 * bc], rstd = stats[2 * bc + 1];
    bool valid = (a < R) && (wc < L);
    float xn = valid ? (x[(size_t)bc * AW + e] - mean) * rstd : 0.f;
    unsigned short* hp = h + (size_t)bc * NF * AW;

    const unsigned short* w2hi = w2bf;
    const unsigned short* w2lo = w2bf + NF * NHID;

    f32x4 acc[4][2];
    #pragma unroll
    for (int t = 0; t < 2; t++) {
        f32x4 bb = *(const f32x4*)(b2 + 16 * t + 4 * g);
        #pragma unroll
        for (int ti = 0; ti < 4; ti++) acc[ti][t] = bb;
    }

    for (int w = 0; w < 4; w++) {
        int jw = 32 * w;
        frag_u Ah[2], Al[2];
        #pragma unroll
        for (int t = 0; t < 2; t++) {
            size_t off = (size_t)(c16 + 16 * t) * NHID + jw + 8 * g;
            const unsigned int* ph = (const unsigned int*)(w2hi + off);
            const unsigned int* pl = (const unsigned int*)(w2lo + off);
            #pragma unroll
            for (int d = 0; d < 4; d++) { Ah[t].u[d] = ph[d]; Al[t].u[d] = pl[d]; }
        }

        #pragma unroll 4
        for (int jp = 0; jp < 16; jp++) {
            int j0 = jw + 2 * jp;
            float v0 = fmaxf(fmaf(xn, w1[j0], b1[j0]), 0.f);
            float v1 = fmaxf(fmaf(xn, w1[j0 + 1], b1[j0 + 1]), 0.f);
            unsigned int hi, lo;
            pack_hilo(v0, v1, hi, lo);
            hid_hi[tid * HSTR + jp] = hi;
            hid_lo[tid * HSTR + jp] = lo;
        }
        __syncthreads();

        #pragma unroll
        for (int ti = 0; ti < 4; ti++) {
            int el = (wv * 4 + ti) * 16 + c16;
            const unsigned int* bh = &hid_hi[el * HSTR + 4 * g];
            const unsigned int* bl = &hid_lo[el * HSTR + 4 * g];
            frag_u Bh, Bl;
            #pragma unroll
            for (int d = 0; d < 4; d++) { Bh.u[d] = bh[d]; Bl.u[d] = bl[d]; }
            #pragma unroll
            for (int t = 0; t < 2; t++) {
                acc[ti][t] = __builtin_amdgcn_mfma_f32_16x16x32_bf16(Ah[t].s, Bh.s, acc[ti][t], 0, 0, 0);
                acc[ti][t] = __builtin_amdgcn_mfma_f32_16x16x32_bf16(Al[t].s, Bh.s, acc[ti][t], 0, 0, 0);
                acc[ti][t] = __builtin_amdgcn_mfma_f32_16x16x32_bf16(Ah[t].s, Bl.s, acc[ti][t], 0, 0, 0);
            }
        }
        __syncthreads();
    }

    // ---- pool LDS accumulators (alias dead hid_hi)
    float* col_lds = (float*)hid_hi;
    float* row_lds = col_lds + 96 * 9;
    float* mat_lds = row_lds + 32;
    unsigned* max_lds = (unsigned*)(mat_lds + 8);
    for (int i = tid; i < 96 * 9 + 32 + 8 + 32; i += 256) col_lds[i] = 0.f;
    __syncthreads();

    int a0 = base / NW;
    float matp[2] = {0.f, 0.f};
    float mxp[2][4];
    #pragma unroll
    for (int t = 0; t < 2; t++)
        #pragma unroll
        for (int r = 0; r < 4; r++) mxp[t][r] = -FLT_MAX;

    #pragma unroll
    for (int ti = 0; ti < 4; ti++) {
        int el = (wv * 4 + ti) * 16 + c16;
        int ee = base + el;
        int aa = ee / NW, ww = ee - aa * NW;
        float mk = (aa < R && ww < L) ? 1.f : 0.f;
        float rowv[2];
        #pragma unroll
        for (int t = 0; t < 2; t++) {
            #pragma unroll
            for (int r = 0; r < 4; r++) {
                int f = 4 * g + r + 16 * t;
                float hv = acc[ti][t][r] * mk;
                hp[(size_t)f * AW + ee] = bf16rne(hv);
                mxp[t][r] = fmaxf(mxp[t][r], hv);
                if (r == 1)      rowv[t] = __sinf(hv);
                else if (r == 2) atomicAdd(&col_lds[ww * 9 + g + 4 * t], __sinf(hv));
                else if (r == 3) matp[t] += __sinf(hv);
            }
        }
        #pragma unroll
        for (int t = 0; t < 2; t++) {
            float v = grp16_sum(rowv[t]);
            if (c16 == 0) atomicAdd(&row_lds[(aa - a0) * 8 + g + 4 * t], v);
        }
    }

    #pragma unroll
    for (int t = 0; t < 2; t++) {
        float v = grp16_sum(matp[t]);
        if (c16 == 0) atomicAdd(&mat_lds[g + 4 * t], v);
        #pragma unroll
        for (int r = 0; r < 4; r++) {
            float m = grp16_max(mxp[t][r]);
            if (c16 == 0) atomicMax(&max_lds[4 * g + r + 16 * t], fkey(m));
        }
    }
    __syncthreads();
    if (tid < 32) {
        int ar = a0 + (tid >> 3);
        if (ar < NA) atomicAdd(&rowsum[(bc * NA + ar) * 8 + (tid & 7)], row_lds[tid]);
    }
    if (tid < 8) atomicAdd(&matsum[bc * 8 + tid], mat_lds[tid]);
    if (tid >= 32 && tid < 64) atomicMax(&cmax_key[bc * NF + tid - 32], max_lds[tid - 32]);
    for (int i = tid; i < NW * 8; i += 256)
        atomicAdd(&colsum[bc * NW * 8 + i], col_lds[(i >> 3) * 9 + (i & 7)]);
}

// ---------------------------------------------------------------- precompute per-(bc): rowc[j][a], colc[j][w]
__global__ __launch_bounds__(256) void precomp_kernel(
    const float* __restrict__ rowsum, const float* __restrict__ colsum,
    const float* __restrict__ matsum, const unsigned* __restrict__ cmax_key,
    const float* __restrict__ w1, const float* __restrict__ b1,
    float* __restrict__ rowc, float* __restrict__ colc)
{
    __shared__ float sbm[NF];
    __shared__ float sconst[NHID];
    __shared__ float scs[NW * 8];
    int tid = threadIdx.x;
    int bc = blockIdx.x, b = bc / NC;

    for (int i = tid; i < NW * 8; i += 256) scs[i] = colsum[bc * NW * 8 + i];
    if (tid < NF) {
        unsigned km = cmax_key[(b * NC) * NF + tid];
        for (int c = 1; c < NC; c++) {
            unsigned kc = cmax_key[(b * NC + c) * NF + tid];
            km = (kc > km) ? kc : km;
        }
        sbm[tid] = funkey(km);
    }
    __syncthreads();
    if (tid < NHID) {
        float v = b1[tid];
        const float* mp = matsum + bc * 8;
        #pragma unroll
        for (int k = 0; k < 8; k++) v = fmaf(mp[k], w1[(24 + k) * NHID + tid], v);
        #pragma unroll
        for (int f = 0; f < NF; f++) v = fmaf(sbm[f], w1[(32 + f) * NHID + tid], v);
        sconst[tid] = v;
    }
    __syncthreads();
    for (int i = tid; i < NHID * NA; i += 256) {
        int j = i / NA, aa = i - j * NA;
        const float* rp = rowsum + (bc * NA + aa) * 8;
        float v = sconst[j];
        #pragma unroll
        for (int k = 0; k < 8; k++) v = fmaf(rp[k], w1[(8 + k) * NHID + j], v);
        rowc[(size_t)bc * (NHID * NA) + i] = v;
    }
    for (int i = tid; i < NHID * NW; i += 256) {
        int j = i / NW, ww = i - j * NW;
        float v = 0.f;
        #pragma unroll
        for (int k = 0; k < 8; k++) v = fmaf(scs[ww * 8 + k], w1[(16 + k) * NHID + j], v);
        colc[(size_t)bc * (NHID * NW) + i] = v;
    }
}

// ---------------------------------------------------------------- shared mlp core (phases A+B), returns acc
// r19: rowc block-slice ([128 j][3 a] = 1.5 KB) staged in LDS at entry;
// phase A's rowc seed becomes an LDS read (lgkm queue, broadcast-friendly),
// halving the per-jp global-load count (4 -> 2, colc only). Values identical.
__device__ __forceinline__ void mlp_core(
    int tid, int bc, int base, int a, int wc, int g, int c16, int wv,
    const unsigned short* hp, const float* rcr, const float* rcc,
    const float* __restrict__ w1t, const unsigned short* __restrict__ w2bf,
    const float* __restrict__ b2, unsigned int* hid_hi, unsigned int* hid_lo,
    float* srow, f32x4 (&acc)[4][2])
{
    int e = base + tid;
    int a0 = base / NW;
    int da = a - a0;

    // stage rowc slice: srow[j*4 + d] = rowc[j][a0+d], d in 0..2
    for (int i = tid; i < NHID * 4; i += 256) {
        int j = i >> 2, d = i & 3;
        int aa = a0 + d;
        srow[i] = (d < 3 && aa < NA) ? rcr[(size_t)j * NA + aa] : 0.f;
    }

    float p[8];
    #pragma unroll
    for (int k = 0; k < 8; k++) p[k] = __sinf(bf2f(hp[(size_t)(4 * k) * AW + e]));
    v2f p2[4];
    #pragma unroll
    for (int t = 0; t < 4; t++) p2[t] = (v2f){p[2 * t], p[2 * t + 1]};

    const unsigned short* w2hi = w2bf;
    const unsigned short* w2lo = w2bf + NF * NHID;

    #pragma unroll
    for (int t = 0; t < 2; t++) {
        f32x4 bb = *(const f32x4*)(b2 + 16 * t + 4 * g);
        #pragma unroll
        for (int ti = 0; ti < 4; ti++) acc[ti][t] = bb;
    }
    __syncthreads();   // srow staged before phase A reads it

    for (int w = 0; w < 4; w++) {
        int jw = 32 * w;
        frag_u Ah[2], Al[2];
        #pragma unroll
        for (int t = 0; t < 2; t++) {
            size_t off = (size_t)(c16 + 16 * t) * NHID + jw + 8 * g;
            const unsigned int* ph = (const unsigned int*)(w2hi + off);
            const unsigned int* pl = (const unsigned int*)(w2lo + off);
            #pragma unroll
            for (int d = 0; d < 4; d++) { Ah[t].u[d] = ph[d]; Al[t].u[d] = pl[d]; }
        }

        #pragma unroll 4
        for (int jp = 0; jp < 16; jp++) {
            int jl = 2 * jp;
            const v2f* w1r0 = (const v2f*)(w1t + (size_t)(jw + jl) * 24);
            const v2f* w1r1 = w1r0 + 12;
            v2f u0 = {srow[(jw + jl) * 4 + da], rcc[(size_t)(jw + jl) * NW + wc]};
            v2f u1 = {srow[(jw + jl + 1) * 4 + da], rcc[(size_t)(jw + jl + 1) * NW + wc]};
            #pragma unroll
            for (int t = 0; t < 4; t++) {
                u0 = PKFMA(p2[t], w1r0[t], u0);
                u1 = PKFMA(p2[t], w1r1[t], u1);
            }
            float v0 = fmaxf(u0.x + u0.y, 0.f);
            float v1 = fmaxf(u1.x + u1.y, 0.f);
            unsigned int hi, lo;
            pack_hilo(v0, v1, hi, lo);
            hid_hi[tid * HSTR + jp] = hi;
            hid_lo[tid * HSTR + jp] = lo;
        }
        __syncthreads();

        #pragma unroll
        for (int ti = 0; ti < 4; ti++) {
            int el = (wv * 4 + ti) * 16 + c16;
            const unsigned int* bh = &hid_hi[el * HSTR + 4 * g];
            const unsigned int* bl = &hid_lo[el * HSTR + 4 * g];
            frag_u Bh, Bl;
            #pragma unroll
            for (int d = 0; d < 4; d++) { Bh.u[d] = bh[d]; Bl.u[d] = bl[d]; }
            #pragma unroll
            for (int t = 0; t < 2; t++) {
                acc[ti][t] = __builtin_amdgcn_mfma_f32_16x16x32_bf16(Ah[t].s, Bh.s, acc[ti][t], 0, 0, 0);
                acc[ti][t] = __builtin_amdgcn_mfma_f32_16x16x32_bf16(Al[t].s, Bh.s, acc[ti][t], 0, 0, 0);
                acc[ti][t] = __builtin_amdgcn_mfma_f32_16x16x32_bf16(Ah[t].s, Bl.s, acc[ti][t], 0, 0, 0);
            }
        }
        __syncthreads();
    }
}

// ---------------------------------------------------------------- mlp_mid: stacks 0..2 — write h + fused pools
__global__ __launch_bounds__(256, 4) void mlp_mid_kernel(
    unsigned short* __restrict__ h, const float* __restrict__ rowc,
    const float* __restrict__ colc, const int* __restrict__ rows_len,
    const int* __restrict__ cols_len, const float* __restrict__ w1t,
    const unsigned short* __restrict__ w2bf, const float* __restrict__ b2,
    float* __restrict__ rowsum, float* __restrict__ colsum,
    float* __restrict__ matsum, unsigned* __restrict__ cmax_key)
{
    __shared__ unsigned int hid_hi[256 * HSTR];
    __shared__ unsigned int hid_lo[256 * HSTR];
    __shared__ float srow[NHID * 4];

    int tid = threadIdx.x;
    int bc = blockIdx.x / 36;
    int blk36 = blockIdx.x % 36;
    int base = blk36 * 256;
    int lane = tid & 63, wv = tid >> 6;
    int g = lane >> 4, c16 = lane & 15;
    int e = base + tid;
    int a = e / NW, wc = e - a * NW;
    unsigned short* hp = h + (size_t)bc * NF * AW;
    const float* rcr = rowc + (size_t)bc * (NHID * NA);
    const float* rcc = colc + (size_t)bc * (NHID * NW);

    f32x4 acc[4][2];
    mlp_core(tid, bc, base, a, wc, g, c16, wv, hp, rcr, rcc, w1t, w2bf, b2,
             hid_hi, hid_lo, srow, acc);

    float* col_lds = (float*)hid_hi;
    float* row_lds = col_lds + 96 * 9;
    float* mat_lds = row_lds + 32;
    unsigned* max_lds = (unsigned*)(mat_lds + 8);
    for (int i = tid; i < 96 * 9 + 32 + 8 + 32; i += 256) col_lds[i] = 0.f;
    __syncthreads();

    int R = rows_len[bc], L = cols_len[bc];
    int a0 = base / NW;
    float matp[2] = {0.f, 0.f};
    float mxp[2][4];
    #pragma unroll
    for (int t = 0; t < 2; t++)
        #pragma unroll
        for (int r = 0; r < 4; r++) mxp[t][r] = -FLT_MAX;

    #pragma unroll
    for (int ti = 0; ti < 4; ti++) {
        int el = (wv * 4 + ti) * 16 + c16;
        int ee = base + el;
        int aa = ee / NW, ww = ee - aa * NW;
        float mk = (aa < R && ww < L) ? 1.f : 0.f;
        float rowv[2];
        #pragma unroll
        for (int t = 0; t < 2; t++) {
            #pragma unroll
            for (int r = 0; r < 4; r++) {
                int f = 4 * g + r + 16 * t;
                unsigned short* ad = hp + (size_t)f * AW + ee;
                float hv = (bf2f(*ad) + acc[ti][t][r]) * mk;
                *ad = bf16rne(hv);
                mxp[t][r] = fmaxf(mxp[t][r], hv);
                if (r == 1)      rowv[t] = __sinf(hv);
                else if (r == 2) atomicAdd(&col_lds[ww * 9 + g + 4 * t], __sinf(hv));
                else if (r == 3) matp[t] += __sinf(hv);
            }
        }
        #pragma unroll
        for (int t = 0; t < 2; t++) {
            float v = grp16_sum(rowv[t]);
            if (c16 == 0) atomicAdd(&row_lds[(aa - a0) * 8 + g + 4 * t], v);
        }
    }

    #pragma unroll
    for (int t = 0; t < 2; t++) {
        float v = grp16_sum(matp[t]);
        if (c16 == 0) atomicAdd(&mat_lds[g + 4 * t], v);
        #pragma unroll
        for (int r = 0; r < 4; r++) {
            float m = grp16_max(mxp[t][r]);
            if (c16 == 0) atomicMax(&max_lds[4 * g + r + 16 * t], fkey(m));
        }
    }
    __syncthreads();
    if (tid < 32) {
        int ar = a0 + (tid >> 3);
        if (ar < NA) atomicAdd(&rowsum[(bc * NA + ar) * 8 + (tid & 7)], row_lds[tid]);
    }
    if (tid < 8) atomicAdd(&matsum[bc * 8 + tid], mat_lds[tid]);
    if (tid >= 32 && tid < 64) atomicMax(&cmax_key[bc * NF + tid - 32], max_lds[tid - 32]);
    for (int i = tid; i < NW * 8; i += 256)
        atomicAdd(&colsum[bc * NW * 8 + i], col_lds[(i >> 3) * 9 + (i & 7)]);
}

// ---------------------------------------------------------------- mlp_last: stack 3 — sqsum only, no h write
__global__ __launch_bounds__(256, 4) void mlp_last_kernel(
    unsigned short* __restrict__ h, const float* __restrict__ rowc,
    const float* __restrict__ colc, const int* __restrict__ rows_len,
    const int* __restrict__ cols_len, const float* __restrict__ w1t,
    const unsigned short* __restrict__ w2bf, const float* __restrict__ b2,
    float* __restrict__ sqsum)
{
    __shared__ unsigned int hid_hi[256 * HSTR];
    __shared__ unsigned int hid_lo[256 * HSTR];
    __shared__ float srow[NHID * 4];

    int tid = threadIdx.x;
    int bc = blockIdx.x / 36;
    int blk36 = blockIdx.x % 36;
    int base = blk36 * 256;
    int lane = tid & 63, wv = tid >> 6;
    int g = lane >> 4, c16 = lane & 15;
    int e = base + tid;
    int a = e / NW, wc = e - a * NW;
    unsigned short* hp = h + (size_t)bc * NF * AW;
    const float* rcr = rowc + (size_t)bc * (NHID * NA);
    const float* rcc = colc + (size_t)bc * (NHID * NW);

    f32x4 acc[4][2];
    mlp_core(tid, bc, base, a, wc, g, c16, wv, hp, rcr, rcc, w1t, w2bf, b2,
             hid_hi, hid_lo, srow, acc);

    int R = rows_len[bc], L = cols_len[bc];
    float psum[2][4] = {{0.f, 0.f, 0.f, 0.f}, {0.f, 0.f, 0.f, 0.f}};
    #pragma unroll
    for (int ti = 0; ti < 4; ti++) {
        int el = (wv * 4 + ti) * 16 + c16;
        int ee = base + el;
        int aa = ee / NW, ww = ee - aa * NW;
        float mk = (aa < R && ww < L) ? 1.f : 0.f;
        #pragma unroll
        for (int t = 0; t < 2; t++) {
            #pragma unroll
            for (int r = 0; r < 4; r++) {
                int f = 4 * g + r + 16 * t;
                float hv = (bf2f(hp[(size_t)f * AW + ee]) + acc[ti][t][r]) * mk;
                psum[t][r] = fmaf(hv, hv, psum[t][r]);
            }
        }
    }
    float* sq_lds = (float*)hid_hi;
    if (tid < NF) sq_lds[tid] = 0.f;
    __syncthreads();
    #pragma unroll
    for (int t = 0; t < 2; t++) {
        #pragma unroll
        for (int r = 0; r < 4; r++) {
            float v = grp16_sum(psum[t][r]);
            if (c16 == 0) atomicAdd(&sq_lds[4 * g + r + 16 * t], v);
        }
    }
    __syncthreads();
    if (tid < NF) atomicAdd(&sqsum[bc * NF + tid], sq_lds[tid]);
}

// ---------------------------------------------------------------- final: rms from sqsum + mean-over-C + MLP + tanh
__global__ __launch_bounds__(64) void out_kernel(
    const float* __restrict__ sqsum, const int* __restrict__ rows_len,
    const int* __restrict__ cols_len, const float* __restrict__ w1,
    const float* __restrict__ b1, const float* __restrict__ w2,
    const float* __restrict__ b2, float* __restrict__ out)
{
    int b = threadIdx.x;
    if (b >= NB) return;
    float hm[NF];
    #pragma unroll
    for (int f = 0; f < NF; f++) hm[f] = 0.f;
    for (int c = 0; c < NC; c++) {
        int bc = b * NC + c;
        float n = (float)(rows_len[bc] * cols_len[bc]);
        float rdn = 1.f / fmaxf(n, 1e-12f);
        #pragma unroll
        for (int f = 0; f < NF; f++) {
            float q = fmaxf(sqsum[bc * NF + f], 1e-20f);
            hm[f] += sqrtf(q * rdn);
        }
    }
    #pragma unroll
    for (int f = 0; f < NF; f++) hm[f] *= (1.f / (float)NC);

    float o0 = b2[0], o1 = b2[1];
    for (int j = 0; j < NHID; j++) {
        float v = b1[j];
        #pragma unroll
        for (int f = 0; f < NF; f++) v = fmaf(hm[f], w1[f * NHID + j], v);
        v = fmaxf(v, 0.f);
        o0 = fmaf(v, w2[j * 2 + 0], o0);
        o1 = fmaf(v, w2[j * 2 + 1], o1);
    }
    out[b * 2 + 0] = 8.f * tanhf(o0);
    out[b * 2 + 1] = 8.f * tanhf(o1);
}

// ---------------------------------------------------------------- launcher
extern "C" void kernel_launch(void* const* d_in, const int* in_sizes, int n_in,
                              void* d_out, int out_size, void* d_ws, size_t ws_size,
                              hipStream_t stream)
{
    const float* x    = (const float*)d_in[0];
    const int* rl     = (const int*)d_in[1];
    const int* cl     = (const int*)d_in[2];
    const float* t0w1 = (const float*)d_in[3];
    const float* t0b1 = (const float*)d_in[4];
    const float* t0w2 = (const float*)d_in[5];
    const float* t0b2 = (const float*)d_in[6];
    const float* tw1  = (const float*)d_in[7];
    const float* tb1  = (const float*)d_in[8];
    const float* tw2  = (const float*)d_in[9];
    const float* tb2  = (const float*)d_in[10];
    const float* ow1  = (const float*)d_in[11];
    const float* ob1  = (const float*)d_in[12];
    const float* ow2  = (const float*)d_in[13];
    const float* ob2  = (const float*)d_in[14];
    float* out = (float*)d_out;

    float* ws    = (float*)d_ws;
    unsigned short* h = (unsigned short*)ws;         // NEL*NF ushorts (region sized as floats; half used)
    float* stats = ws + NEL * NF;                    // 2*NBC
    // --- contiguous accumulator region (single small memset per stack) ---
    float*    rowb = stats + 2 * NBC;                // NBC*NA*8 = 147456
    float*    matb = rowb + (size_t)NBC * NA * 8;    // NBC*8    = 1536
    unsigned* cmxb = (unsigned*)(matb + NBC * 8);    // NBC*NF   = 6144
    float*    colb = (float*)(cmxb + NBC * NF);      // NBC*NW*8 = 147456
    size_t    accum_floats = (size_t)NBC * NA * 8 + NBC * 8 + NBC * NF
                           + (size_t)NBC * NW * 8;   // 302592 floats = 1.2 MB
    // --- rest ---
    float* sqb   = colb + (size_t)NBC * NW * 8;      // NBC*NF
    float* w1tb  = sqb + NBC * NF;                   // 4*NHID*24
    float* rowcb = w1tb + 4 * NHID * 24;             // NBC*NHID*NA
    float* colcb = rowcb + (size_t)NBC * NHID * NA;  // NBC*NHID*NW
    unsigned short* w2bfb = (unsigned short*)(colcb + (size_t)NBC * NHID * NW); // 4*2*NF*NHID
    unsigned short* w2t0b = w2bfb + (size_t)4 * 2 * NF * NHID;                  // 2*NF*NHID

    hipMemsetAsync(sqb, 0, NBC * NF * sizeof(float), stream);
    hipMemsetAsync(rowb, 0, accum_floats * sizeof(float), stream);  // for t0's fused pools
    stats_kernel<<<NBC, 256, 0, stream>>>(x, rl, cl, stats);
    prep_kernel<<<(4 * NHID * 24 + 255) / 256, 256, 0, stream>>>(tw1, w1tb);
    prep2_kernel<<<(4 * NF * NHID + 255) / 256, 256, 0, stream>>>(tw2, w2bfb);
    prep2t_kernel<<<(NF * NHID + 255) / 256, 256, 0, stream>>>(t0w2, w2t0b);
    t0_kernel<<<NBC * 36, 256, 0, stream>>>(x, rl, cl, stats,
                                            t0w1, t0b1, w2t0b, t0b2, h,
                                            rowb, colb, matb, cmxb);
    for (int s = 0; s < 4; s++) {
        precomp_kernel<<<NBC, 256, 0, stream>>>(rowb, colb, matb, cmxb,
            tw1 + (size_t)s * 64 * NHID, tb1 + s * NHID, rowcb, colcb);
        if (s < 3) {
            hipMemsetAsync(rowb, 0, accum_floats * sizeof(float), stream);
            mlp_mid_kernel<<<NBC * 36, 256, 0, stream>>>(h, rowcb, colcb, rl, cl,
                w1tb + (size_t)s * NHID * 24,
                w2bfb + (size_t)s * (2 * NF * NHID),
                tb2 + s * NF, rowb, colb, matb, cmxb);
        } else {
            mlp_last_kernel<<<NBC * 36, 256, 0, stream>>>(h, rowcb, colcb, rl, cl,
                w1tb + (size_t)s * NHID * 24,
                w2bfb + (size_t)s * (2 * NF * NHID),
                tb2 + s * NF, sqb);
        }
    }
    out_kernel<<<1, 64, 0, stream>>>(sqb, rl, cl, ow1, ob1, ow2, ob2, out);
}